// Round 3
// baseline (85.105 us; speedup 1.0000x reference)
//
#include <hip/hip_runtime.h>

#define AR 8
#define SEQ 4096
#define BATCH 8192
#define OUTW (AR + SEQ)   // 4104 floats per output row
#define LROWS 1024        // rows of C kept in LDS (32 KB)

typedef float f32x4 __attribute__((ext_vector_type(4)));

// ---------------- Phase 1: coefficient matrix via LDS log-doubling ----------------
// C[t][j]: pred_t = sum_j C[t][j] * y[j].
// Advance (right-multiply by companion A): (R*A)_j = R_{j-1} + R_7 * w_j  (R_{-1}=0)
__global__ __launch_bounds__(1024) void coeff_kernel(const float* __restrict__ W,
                                                     float* __restrict__ C) {
    __shared__ float Cs[LROWS][AR];          // 32 KB
    __shared__ float w[AR];
    __shared__ float M[AR][AR];              // A^m during loop; A^1024 after
    __shared__ float Mn[AR][AR];             // scratch; A^2048 in epilogue
    const int tid = threadIdx.x;

    if (tid < AR) w[tid] = W[tid];
    __syncthreads();

    // Seed rows 0..7 (thread 0, trivial) and M = A^8 (threads 0..7, row each).
    if (tid == 0) {
        float c[AR];
        #pragma unroll
        for (int j = 0; j < AR; ++j) c[j] = w[j];
        for (int t = 0; t < AR; ++t) {
            #pragma unroll
            for (int j = 0; j < AR; ++j) Cs[t][j] = c[j];
            float c7 = c[AR - 1];
            float nc[AR];
            #pragma unroll
            for (int j = AR - 1; j >= 1; --j) nc[j] = c[j - 1] + c7 * w[j];
            nc[0] = c7 * w[0];
            #pragma unroll
            for (int j = 0; j < AR; ++j) c[j] = nc[j];
        }
    }
    if (tid < AR) {
        float r[AR];
        #pragma unroll
        for (int j = 0; j < AR; ++j) r[j] = (j == tid) ? 1.f : 0.f;
        for (int s = 0; s < AR; ++s) {
            float r7 = r[AR - 1];
            float nr[AR];
            #pragma unroll
            for (int j = AR - 1; j >= 1; --j) nr[j] = r[j - 1] + r7 * w[j];
            nr[0] = r7 * w[0];
            #pragma unroll
            for (int j = 0; j < AR; ++j) r[j] = nr[j];
        }
        #pragma unroll
        for (int j = 0; j < AR; ++j) M[tid][j] = r[j];
    }
    __syncthreads();

    // LDS doubling: m = 8..512 -> fills rows [0,1024); M ends as A^1024.
    for (int m = AR; m < LROWS; m <<= 1) {
        float nr[AR];
        if (tid < m) {
            float ci[AR];
            #pragma unroll
            for (int k = 0; k < AR; ++k) ci[k] = Cs[tid][k];
            #pragma unroll
            for (int j = 0; j < AR; ++j) {
                float s = 0.f;
                #pragma unroll
                for (int k = 0; k < AR; ++k) s += ci[k] * M[k][j];
                nr[j] = s;
            }
        }
        float mnv = 0.f;
        if (tid < 64) {
            const int k = tid >> 3, j = tid & 7;
            #pragma unroll
            for (int q = 0; q < AR; ++q) mnv += M[k][q] * M[q][j];
        }
        __syncthreads();      // all reads of M / Cs[0,m) done
        if (tid < m) {
            #pragma unroll
            for (int j = 0; j < AR; ++j) Cs[m + tid][j] = nr[j];
        }
        if (tid < 64) M[tid >> 3][tid & 7] = mnv;
        __syncthreads();
    }

    // Mn = M*M = A^2048
    if (tid < 64) {
        const int k = tid >> 3, j = tid & 7;
        float s = 0.f;
        #pragma unroll
        for (int q = 0; q < AR; ++q) s += M[k][q] * M[q][j];
        Mn[k][j] = s;
    }
    __syncthreads();

    // Epilogue: thread tid owns LDS row tid; emits global rows tid, tid+1024(,·A^1024),
    // tid+2048(,·A^2048), tid+3072(,·A^1024·A^2048).
    {
        float ci[AR];
        #pragma unroll
        for (int k = 0; k < AR; ++k) ci[k] = Cs[tid][k];

        float r1[AR], r2[AR], r3[AR];
        #pragma unroll
        for (int j = 0; j < AR; ++j) {
            float s = 0.f;
            #pragma unroll
            for (int k = 0; k < AR; ++k) s += ci[k] * M[k][j];      // * A^1024
            r1[j] = s;
        }
        #pragma unroll
        for (int j = 0; j < AR; ++j) {
            float s = 0.f;
            #pragma unroll
            for (int k = 0; k < AR; ++k) s += ci[k] * Mn[k][j];     // * A^2048
            r2[j] = s;
        }
        #pragma unroll
        for (int j = 0; j < AR; ++j) {
            float s = 0.f;
            #pragma unroll
            for (int k = 0; k < AR; ++k) s += r1[k] * Mn[k][j];     // * A^3072
            r3[j] = s;
        }
        f32x4* dst = reinterpret_cast<f32x4*>(C);
        dst[(size_t)tid * 2 + 0] = (f32x4){ci[0], ci[1], ci[2], ci[3]};
        dst[(size_t)tid * 2 + 1] = (f32x4){ci[4], ci[5], ci[6], ci[7]};
        dst[((size_t)tid + 1024) * 2 + 0] = (f32x4){r1[0], r1[1], r1[2], r1[3]};
        dst[((size_t)tid + 1024) * 2 + 1] = (f32x4){r1[4], r1[5], r1[6], r1[7]};
        dst[((size_t)tid + 2048) * 2 + 0] = (f32x4){r2[0], r2[1], r2[2], r2[3]};
        dst[((size_t)tid + 2048) * 2 + 1] = (f32x4){r2[4], r2[5], r2[6], r2[7]};
        dst[((size_t)tid + 3072) * 2 + 0] = (f32x4){r3[0], r3[1], r3[2], r3[3]};
        dst[((size_t)tid + 3072) * 2 + 1] = (f32x4){r3[4], r3[5], r3[6], r3[7]};
    }
}

// ---------------- Phase 2: out = [y | y @ C^T] ----------------
// Thread: 8 consecutive t (32 B contiguous, 2 nontemporal f32x4 stores) x 8 batch rows.
__global__ __launch_bounds__(256) void pred_kernel(const float* __restrict__ y,
                                                   const float* __restrict__ C,
                                                   float* __restrict__ out) {
    const int tt = blockIdx.x * 256 + threadIdx.x;   // 8-wide t group: 0..511
    const int t0 = tt * 8;
    const int row0 = blockIdx.y * 8;

    // 8 C-rows = 64 contiguous floats into registers.
    float c[8][AR];
    const f32x4* Cv = reinterpret_cast<const f32x4*>(C + (size_t)t0 * AR);
    #pragma unroll
    for (int k = 0; k < 8; ++k) {
        f32x4 a = Cv[k * 2 + 0];
        f32x4 b = Cv[k * 2 + 1];
        c[k][0] = a.x; c[k][1] = a.y; c[k][2] = a.z; c[k][3] = a.w;
        c[k][4] = b.x; c[k][5] = b.y; c[k][6] = b.z; c[k][7] = b.w;
    }

    #pragma unroll
    for (int r = 0; r < 8; ++r) {
        const int row = row0 + r;
        const f32x4* yv = reinterpret_cast<const f32x4*>(y + (size_t)row * AR);
        f32x4 ya = yv[0], yb = yv[1];
        float yy[AR] = {ya.x, ya.y, ya.z, ya.w, yb.x, yb.y, yb.z, yb.w};
        float s[8];
        #pragma unroll
        for (int k = 0; k < 8; ++k) {
            float acc = 0.f;
            #pragma unroll
            for (int j = 0; j < AR; ++j) acc += c[k][j] * yy[j];
            s[k] = acc;
        }
        f32x4* dst = reinterpret_cast<f32x4*>(out + (size_t)row * OUTW + AR + t0);
        __builtin_nontemporal_store((f32x4){s[0], s[1], s[2], s[3]}, dst + 0);
        __builtin_nontemporal_store((f32x4){s[4], s[5], s[6], s[7]}, dst + 1);
    }

    // y-head (first 8 output columns) once per row.
    if (blockIdx.x == 0 && threadIdx.x < 16) {
        const int r = threadIdx.x >> 1, part = threadIdx.x & 1;
        const int row = row0 + r;
        reinterpret_cast<f32x4*>(out + (size_t)row * OUTW)[part] =
            reinterpret_cast<const f32x4*>(y + (size_t)row * AR)[part];
    }
}

extern "C" void kernel_launch(void* const* d_in, const int* in_sizes, int n_in,
                              void* d_out, int out_size, void* d_ws, size_t ws_size,
                              hipStream_t stream) {
    const float* y = (const float*)d_in[0];
    // d_in[1] = u  -- unused by the reference computation
    const float* W = (const float*)d_in[2];
    float* out = (float*)d_out;
    float* C = (float*)d_ws;                      // 4096*8 floats = 128 KB scratch

    coeff_kernel<<<1, 1024, 0, stream>>>(W, C);
    pred_kernel<<<dim3(SEQ / 2048, BATCH / 8), 256, 0, stream>>>(y, C, out);
}

// Round 4
// 35.999 us; speedup vs baseline: 2.3641x; 2.3641x over previous
//
#include <hip/hip_runtime.h>

#define AR 8
#define SEQ 4096
#define BATCH 8192
#define OUTW (AR + SEQ)   // 4104 floats per output row
#define LROWS 1024        // rows of C kept in LDS (32 KB)

typedef float f32x4 __attribute__((ext_vector_type(4)));

// ---------------- Phase 1: coefficient matrix via LDS log-doubling ----------------
// C[t][j]: pred_t = sum_j C[t][j] * y[j].
// Advance (right-multiply by companion A): (R*A)_j = R_{j-1} + R_7 * w_j  (R_{-1}=0)
__global__ __launch_bounds__(1024) void coeff_kernel(const float* __restrict__ W,
                                                     float* __restrict__ C) {
    __shared__ float Cs[LROWS][AR];          // 32 KB
    __shared__ float w[AR];
    __shared__ float M[AR][AR];              // A^m during loop; A^1024 after
    __shared__ float Mn[AR][AR];             // scratch; A^2048 in epilogue
    const int tid = threadIdx.x;

    if (tid < AR) w[tid] = W[tid];
    __syncthreads();

    // Seed rows 0..7 (thread 0, trivial) and M = A^8 (threads 0..7, row each).
    if (tid == 0) {
        float c[AR];
        #pragma unroll
        for (int j = 0; j < AR; ++j) c[j] = w[j];
        for (int t = 0; t < AR; ++t) {
            #pragma unroll
            for (int j = 0; j < AR; ++j) Cs[t][j] = c[j];
            float c7 = c[AR - 1];
            float nc[AR];
            #pragma unroll
            for (int j = AR - 1; j >= 1; --j) nc[j] = c[j - 1] + c7 * w[j];
            nc[0] = c7 * w[0];
            #pragma unroll
            for (int j = 0; j < AR; ++j) c[j] = nc[j];
        }
    }
    if (tid < AR) {
        float r[AR];
        #pragma unroll
        for (int j = 0; j < AR; ++j) r[j] = (j == tid) ? 1.f : 0.f;
        for (int s = 0; s < AR; ++s) {
            float r7 = r[AR - 1];
            float nr[AR];
            #pragma unroll
            for (int j = AR - 1; j >= 1; --j) nr[j] = r[j - 1] + r7 * w[j];
            nr[0] = r7 * w[0];
            #pragma unroll
            for (int j = 0; j < AR; ++j) r[j] = nr[j];
        }
        #pragma unroll
        for (int j = 0; j < AR; ++j) M[tid][j] = r[j];
    }
    __syncthreads();

    // LDS doubling: m = 8..512 -> fills rows [0,1024); M ends as A^1024.
    for (int m = AR; m < LROWS; m <<= 1) {
        float nr[AR];
        if (tid < m) {
            float ci[AR];
            #pragma unroll
            for (int k = 0; k < AR; ++k) ci[k] = Cs[tid][k];
            #pragma unroll
            for (int j = 0; j < AR; ++j) {
                float s = 0.f;
                #pragma unroll
                for (int k = 0; k < AR; ++k) s += ci[k] * M[k][j];
                nr[j] = s;
            }
        }
        float mnv = 0.f;
        if (tid < 64) {
            const int k = tid >> 3, j = tid & 7;
            #pragma unroll
            for (int q = 0; q < AR; ++q) mnv += M[k][q] * M[q][j];
        }
        __syncthreads();      // all reads of M / Cs[0,m) done
        if (tid < m) {
            #pragma unroll
            for (int j = 0; j < AR; ++j) Cs[m + tid][j] = nr[j];
        }
        if (tid < 64) M[tid >> 3][tid & 7] = mnv;
        __syncthreads();
    }

    // Mn = M*M = A^2048
    if (tid < 64) {
        const int k = tid >> 3, j = tid & 7;
        float s = 0.f;
        #pragma unroll
        for (int q = 0; q < AR; ++q) s += M[k][q] * M[q][j];
        Mn[k][j] = s;
    }
    __syncthreads();

    // Epilogue: thread tid owns LDS row tid; emits global rows tid, tid+1024(,·A^1024),
    // tid+2048(,·A^2048), tid+3072(,·A^1024·A^2048).
    {
        float ci[AR];
        #pragma unroll
        for (int k = 0; k < AR; ++k) ci[k] = Cs[tid][k];

        float r1[AR], r2[AR], r3[AR];
        #pragma unroll
        for (int j = 0; j < AR; ++j) {
            float s = 0.f;
            #pragma unroll
            for (int k = 0; k < AR; ++k) s += ci[k] * M[k][j];      // * A^1024
            r1[j] = s;
        }
        #pragma unroll
        for (int j = 0; j < AR; ++j) {
            float s = 0.f;
            #pragma unroll
            for (int k = 0; k < AR; ++k) s += ci[k] * Mn[k][j];     // * A^2048
            r2[j] = s;
        }
        #pragma unroll
        for (int j = 0; j < AR; ++j) {
            float s = 0.f;
            #pragma unroll
            for (int k = 0; k < AR; ++k) s += r1[k] * Mn[k][j];     // * A^3072
            r3[j] = s;
        }
        f32x4* dst = reinterpret_cast<f32x4*>(C);
        dst[(size_t)tid * 2 + 0] = (f32x4){ci[0], ci[1], ci[2], ci[3]};
        dst[(size_t)tid * 2 + 1] = (f32x4){ci[4], ci[5], ci[6], ci[7]};
        dst[((size_t)tid + 1024) * 2 + 0] = (f32x4){r1[0], r1[1], r1[2], r1[3]};
        dst[((size_t)tid + 1024) * 2 + 1] = (f32x4){r1[4], r1[5], r1[6], r1[7]};
        dst[((size_t)tid + 2048) * 2 + 0] = (f32x4){r2[0], r2[1], r2[2], r2[3]};
        dst[((size_t)tid + 2048) * 2 + 1] = (f32x4){r2[4], r2[5], r2[6], r2[7]};
        dst[((size_t)tid + 3072) * 2 + 0] = (f32x4){r3[0], r3[1], r3[2], r3[3]};
        dst[((size_t)tid + 3072) * 2 + 1] = (f32x4){r3[4], r3[5], r3[6], r3[7]};
    }
}

// ---------------- Phase 2: out = [y | y @ C^T] ----------------
// Thread: 4 consecutive t (one f32x4, lanes contiguous -> 1KB/wave/store) x 8 batch rows.
// Normal (cached) stores: write-once data evicts at full-line granularity via L2.
__global__ __launch_bounds__(256) void pred_kernel(const float* __restrict__ y,
                                                   const float* __restrict__ C,
                                                   float* __restrict__ out) {
    const int tt = blockIdx.x * 256 + threadIdx.x;   // float4-group along t: 0..1023
    const int t0 = tt * 4;
    const int row0 = blockIdx.y * 8;

    // 4 C-rows = 32 contiguous floats into registers.
    float c[4][AR];
    const f32x4* Cv = reinterpret_cast<const f32x4*>(C + (size_t)t0 * AR);
    #pragma unroll
    for (int k = 0; k < 4; ++k) {
        f32x4 a = Cv[k * 2 + 0];
        f32x4 b = Cv[k * 2 + 1];
        c[k][0] = a.x; c[k][1] = a.y; c[k][2] = a.z; c[k][3] = a.w;
        c[k][4] = b.x; c[k][5] = b.y; c[k][6] = b.z; c[k][7] = b.w;
    }

    // Hoist all 8 y-rows (wave-uniform addresses -> scalar loads).
    float yy[8][AR];
    #pragma unroll
    for (int r = 0; r < 8; ++r) {
        const f32x4* yv = reinterpret_cast<const f32x4*>(y + (size_t)(row0 + r) * AR);
        f32x4 a = yv[0], b = yv[1];
        yy[r][0] = a.x; yy[r][1] = a.y; yy[r][2] = a.z; yy[r][3] = a.w;
        yy[r][4] = b.x; yy[r][5] = b.y; yy[r][6] = b.z; yy[r][7] = b.w;
    }

    #pragma unroll
    for (int r = 0; r < 8; ++r) {
        float s[4];
        #pragma unroll
        for (int k = 0; k < 4; ++k) {
            float acc = 0.f;
            #pragma unroll
            for (int j = 0; j < AR; ++j) acc += c[k][j] * yy[r][j];
            s[k] = acc;
        }
        *reinterpret_cast<f32x4*>(out + (size_t)(row0 + r) * OUTW + AR + t0) =
            (f32x4){s[0], s[1], s[2], s[3]};
    }

    // y-head (first 8 output columns) once per row.
    if (blockIdx.x == 0 && threadIdx.x < 16) {
        const int r = threadIdx.x >> 1, part = threadIdx.x & 1;
        const int row = row0 + r;
        reinterpret_cast<f32x4*>(out + (size_t)row * OUTW)[part] =
            reinterpret_cast<const f32x4*>(y + (size_t)row * AR)[part];
    }
}

extern "C" void kernel_launch(void* const* d_in, const int* in_sizes, int n_in,
                              void* d_out, int out_size, void* d_ws, size_t ws_size,
                              hipStream_t stream) {
    const float* y = (const float*)d_in[0];
    // d_in[1] = u  -- unused by the reference computation
    const float* W = (const float*)d_in[2];
    float* out = (float*)d_out;
    float* C = (float*)d_ws;                      // 4096*8 floats = 128 KB scratch

    coeff_kernel<<<1, 1024, 0, stream>>>(W, C);
    pred_kernel<<<dim3(SEQ / 1024, BATCH / 8), 256, 0, stream>>>(y, C, out);
}